// Round 1
// baseline (2678.758 us; speedup 1.0000x reference)
//
#include <hip/hip_runtime.h>

#define HIDDEN  64
#define T_STEPS 2048
#define N_INPUT 5
#define DT      0.1f
#define LN_EPS  1e-5f
#define ROWS    16                     // batch rows per wave (MFMA N)
#define TANH_K  2.885390081777927f     // 2*log2(e)

typedef short bf16x8 __attribute__((ext_vector_type(8)));
typedef float f32x4  __attribute__((ext_vector_type(4)));

union FragU { uint4 u4; unsigned int u[4]; unsigned short us[8]; bf16x8 v; };

__device__ __forceinline__ unsigned short bf16_trunc(float f) {
    return (unsigned short)(__float_as_uint(f) >> 16);
}
__device__ __forceinline__ float bf16_hi_f32(float f) {
    return __uint_as_float(__float_as_uint(f) & 0xFFFF0000u);
}
// pack bf16-trunc of two floats into one dword (lo half = f0, hi half = f1)
__device__ __forceinline__ unsigned int bf16_pack2(float f0, float f1) {
    return (__float_as_uint(f0) >> 16) | (__float_as_uint(f1) & 0xFFFF0000u);
}
template <int XMASK>
__device__ __forceinline__ float swz_xor(float v) {   // xor within 32-lane halves
    return __uint_as_float(
        __builtin_amdgcn_ds_swizzle(__float_as_uint(v), (XMASK << 10) | 0x1F));
}
__device__ __forceinline__ float bperm(int addr32, float v) {  // lane^32 exchange
    return __uint_as_float(__builtin_amdgcn_ds_bpermute(addr32, __float_as_uint(v)));
}

#define MFMA(A, B, C) __builtin_amdgcn_mfma_f32_16x16x32_bf16((A), (B), (C), 0, 0, 0)

// One wave handles ROWS=16 batch rows and ALL 64 hidden units.
// K-slot permutation g(kk,q,j) = 16*(2kk + (j>>2)) + 4q + (j&3) makes the
// recurrent h -> B^T transport lane-local: the B-frag element lane (q,r)
// supplies at slot (kk,j) is its own accumulator element acc[2kk+(j>>2)][j&3].
// => no barriers, no LDS in the 2048-step loop.
__global__ __launch_bounds__(64, 1) void hlnn_wave(
    const float* __restrict__ x, const float* __restrict__ W_in,
    const float* __restrict__ b_in, const float* __restrict__ tau_param,
    const float* __restrict__ W_rec, const float* __restrict__ ln1_w,
    const float* __restrict__ ln1_b, const float* __restrict__ ln2_w,
    const float* __restrict__ ln2_b, const float* __restrict__ head_W,
    const float* __restrict__ head_b, float* __restrict__ out, int Btot)
{
    const int lane = threadIdx.x & 63;
    const int r    = lane & 15;        // batch row within group (MFMA n / A m)
    const int q    = lane >> 4;        // quad / K-group
    const int g    = blockIdx.x;       // 16-row group
    const int addr32 = ((lane ^ 32) & 63) << 2;

    __shared__ float hnbuf[ROWS][68];  // epilogue only

    // ---- static A fragments (permuted K): A[mt][kk].us[j] = W_rec[g(kk,q,j)][16mt+r]
    FragU Ah[4][2], Al[4][2], AxH[4], AxL[4];
#pragma unroll
    for (int mt = 0; mt < 4; ++mt) {
        const int col = 16 * mt + r;
#pragma unroll
        for (int kk = 0; kk < 2; ++kk)
#pragma unroll
            for (int j = 0; j < 8; ++j) {
                const int gh = 16 * (2 * kk + (j >> 2)) + 4 * q + (j & 3);
                const float wv = W_rec[gh * HIDDEN + col];
                Ah[mt][kk].us[j] = bf16_trunc(wv);
                Al[mt][kk].us[j] = bf16_trunc(wv - bf16_hi_f32(wv));
            }
        // x projection keeps the identity K map: slot 8q+j -> input row 8q+j (<5)
#pragma unroll
        for (int j = 0; j < 8; ++j) {
            const int ks = 8 * q + j;
            const float wv = (ks < N_INPUT) ? W_in[ks * HIDDEN + col] : 0.0f;
            AxH[mt].us[j] = bf16_trunc(wv);
            AxL[mt].us[j] = bf16_trunc(wv - bf16_hi_f32(wv));
        }
    }

    // ---- per-lane constants: lane owns hidden c = 16mt + 4q + e
    float w1K[4][4], b1K[4][4], dec[4][4];
    f32x4 cin[4];
#pragma unroll
    for (int mt = 0; mt < 4; ++mt)
#pragma unroll
        for (int e = 0; e < 4; ++e) {
            const int c = 16 * mt + 4 * q + e;
            w1K[mt][e] = ln1_w[c] * TANH_K;         // fold 2*log2(e) into LN affine
            b1K[mt][e] = ln1_b[c] * TANH_K;
            const float tp  = tau_param[c];
            const float tau = (tp > 20.0f) ? tp : log1pf(expf(tp));   // softplus
            dec[mt][e] = 1.0f - DT / tau;
            cin[mt][e] = b_in[c];                   // MFMA C-init
        }

    const float* xrow = x + (size_t)(g * ROWS + r) * T_STEPS * N_INPUT;

    // initial Bx (t=0). No q-masking needed: Ax is zero for k-slots >= 5, so
    // garbage x values in q>0 lanes multiply A=0 and contribute nothing.
    FragU BxH, BxL;
    {
        const float x0 = xrow[0], x1 = xrow[1], x2 = xrow[2], x3 = xrow[3], x4 = xrow[4];
        BxH.u[0] = bf16_pack2(x0, x1); BxH.u[1] = bf16_pack2(x2, x3);
        BxH.u[2] = bf16_pack2(x4, 0.f); BxH.u[3] = 0u;
        BxL.u[0] = bf16_pack2(x0 - bf16_hi_f32(x0), x1 - bf16_hi_f32(x1));
        BxL.u[1] = bf16_pack2(x2 - bf16_hi_f32(x2), x3 - bf16_hi_f32(x3));
        BxL.u[2] = bf16_pack2(x4 - bf16_hi_f32(x4), 0.f); BxL.u[3] = 0u;
    }

    FragU Bh[2], Bl[2];
    Bh[0].u4 = make_uint4(0,0,0,0); Bh[1].u4 = make_uint4(0,0,0,0);
    Bl[0].u4 = make_uint4(0,0,0,0); Bl[1].u4 = make_uint4(0,0,0,0);
    float h[4][4] = {{0.f,0.f,0.f,0.f},{0.f,0.f,0.f,0.f},
                     {0.f,0.f,0.f,0.f},{0.f,0.f,0.f,0.f}};

    for (int t = 0; t < T_STEPS; ++t) {
        // prefetch next step's x (hidden under MFMA + LN phases)
        const size_t toff = (size_t)((t + 1 < T_STEPS) ? (t + 1) : t) * N_INPUT;
        const float xf0 = xrow[toff + 0], xf1 = xrow[toff + 1], xf2 = xrow[toff + 2],
                    xf3 = xrow[toff + 3], xf4 = xrow[toff + 4];

        // pre^T = b_in + W_in^T.x^T + W_rec^T.h^T : 9 MFMAs per tile,
        // 4 independent acc chains interleaved product-major for ILP.
        f32x4 acc[4];
#pragma unroll
        for (int mt = 0; mt < 4; ++mt) acc[mt] = MFMA(AxH[mt].v, BxH.v, cin[mt]);
#pragma unroll
        for (int mt = 0; mt < 4; ++mt) acc[mt] = MFMA(AxH[mt].v, BxL.v, acc[mt]);
#pragma unroll
        for (int mt = 0; mt < 4; ++mt) acc[mt] = MFMA(AxL[mt].v, BxH.v, acc[mt]);
#pragma unroll
        for (int mt = 0; mt < 4; ++mt) acc[mt] = MFMA(Ah[mt][0].v, Bh[0].v, acc[mt]);
#pragma unroll
        for (int mt = 0; mt < 4; ++mt) acc[mt] = MFMA(Ah[mt][0].v, Bl[0].v, acc[mt]);
#pragma unroll
        for (int mt = 0; mt < 4; ++mt) acc[mt] = MFMA(Al[mt][0].v, Bh[0].v, acc[mt]);
#pragma unroll
        for (int mt = 0; mt < 4; ++mt) acc[mt] = MFMA(Ah[mt][1].v, Bh[1].v, acc[mt]);
#pragma unroll
        for (int mt = 0; mt < 4; ++mt) acc[mt] = MFMA(Ah[mt][1].v, Bl[1].v, acc[mt]);
#pragma unroll
        for (int mt = 0; mt < 4; ++mt) acc[mt] = MFMA(Al[mt][1].v, Bh[1].v, acc[mt]);

        // LN stats: lane's 16 values all belong to row r; reduce over the
        // 4 q-lanes of that row, fully in-wave (no LDS storage, no barrier).
        float p1[4], p2[4];
#pragma unroll
        for (int mt = 0; mt < 4; ++mt) {
            p1[mt] = (acc[mt][0] + acc[mt][1]) + (acc[mt][2] + acc[mt][3]);
            p2[mt] = fmaf(acc[mt][0], acc[mt][0], fmaf(acc[mt][1], acc[mt][1],
                     fmaf(acc[mt][2], acc[mt][2], acc[mt][3] * acc[mt][3])));
        }
        float s1 = (p1[0] + p1[1]) + (p1[2] + p1[3]);
        float s2 = (p2[0] + p2[1]) + (p2[2] + p2[3]);
        s1 += swz_xor<16>(s1);  s2 += swz_xor<16>(s2);
        s1 += bperm(addr32, s1); s2 += bperm(addr32, s2);

        // convert prefetched x -> next Bx frags (fills the DS-wait shadow)
        FragU nBxH, nBxL;
        nBxH.u[0] = bf16_pack2(xf0, xf1); nBxH.u[1] = bf16_pack2(xf2, xf3);
        nBxH.u[2] = bf16_pack2(xf4, 0.f); nBxH.u[3] = 0u;
        nBxL.u[0] = bf16_pack2(xf0 - bf16_hi_f32(xf0), xf1 - bf16_hi_f32(xf1));
        nBxL.u[1] = bf16_pack2(xf2 - bf16_hi_f32(xf2), xf3 - bf16_hi_f32(xf3));
        nBxL.u[2] = bf16_pack2(xf4 - bf16_hi_f32(xf4), 0.f); nBxL.u[3] = 0u;

        const float mu   = s1 * (1.0f / 64.0f);
        float var        = fmaf(mu, -mu, s2 * (1.0f / 64.0f));
        var              = fmaxf(var, 0.0f);
        const float rstd = __builtin_amdgcn_rsqf(var + LN_EPS);

        // f = tanh(LN(pre)); h = clip(decay*h + dt*f).  K folded into w1K/b1K;
        // |LN out| <= sqrt(63) so no exp-range clamp needed.
#pragma unroll
        for (int mt = 0; mt < 4; ++mt)
#pragma unroll
            for (int e = 0; e < 4; ++e) {
                const float a1 = rstd * w1K[mt][e];
                const float tt = fmaf(acc[mt][e], a1, fmaf(-mu, a1, b1K[mt][e]));
                const float ex = exp2f(tt);
                const float rc = __builtin_amdgcn_rcpf(ex + 1.0f);
                const float dtf = fmaf(DT, ex, -DT) * rc;     // DT * tanh
                const float hv  = fmaf(dec[mt][e], h[mt][e], dtf);
                h[mt][e] = fminf(fmaxf(hv, -10.0f), 10.0f);
            }

        // repack h -> B-frags entirely in-register (the K-permutation payoff):
        // Bh[kk] = { P[2kk][0], P[2kk][1], P[2kk+1][0], P[2kk+1][1] }
#pragma unroll
        for (int mt = 0; mt < 4; ++mt) {
            const unsigned int hi0 = bf16_pack2(h[mt][0], h[mt][1]);
            const unsigned int hi1 = bf16_pack2(h[mt][2], h[mt][3]);
            const unsigned int lo0 = bf16_pack2(h[mt][0] - bf16_hi_f32(h[mt][0]),
                                                h[mt][1] - bf16_hi_f32(h[mt][1]));
            const unsigned int lo1 = bf16_pack2(h[mt][2] - bf16_hi_f32(h[mt][2]),
                                                h[mt][3] - bf16_hi_f32(h[mt][3]));
            Bh[mt >> 1].u[2 * (mt & 1) + 0] = hi0;
            Bh[mt >> 1].u[2 * (mt & 1) + 1] = hi1;
            Bl[mt >> 1].u[2 * (mt & 1) + 0] = lo0;
            Bl[mt >> 1].u[2 * (mt & 1) + 1] = lo1;
        }

        BxH = nBxH; BxL = nBxL;
    }

    // ---- epilogue: LN2 on final h, then 5x4 heads ----
    {
        float p1[4], p2[4];
#pragma unroll
        for (int mt = 0; mt < 4; ++mt) {
            p1[mt] = (h[mt][0] + h[mt][1]) + (h[mt][2] + h[mt][3]);
            p2[mt] = fmaf(h[mt][0], h[mt][0], fmaf(h[mt][1], h[mt][1],
                     fmaf(h[mt][2], h[mt][2], h[mt][3] * h[mt][3])));
        }
        float s1 = (p1[0] + p1[1]) + (p1[2] + p1[3]);
        float s2 = (p2[0] + p2[1]) + (p2[2] + p2[3]);
        s1 += swz_xor<16>(s1);  s2 += swz_xor<16>(s2);
        s1 += bperm(addr32, s1); s2 += bperm(addr32, s2);
        const float mu   = s1 * (1.0f / 64.0f);
        float var        = fmaf(mu, -mu, s2 * (1.0f / 64.0f));
        var              = fmaxf(var, 0.0f);
        const float rstd = __builtin_amdgcn_rsqf(var + LN_EPS);
#pragma unroll
        for (int mt = 0; mt < 4; ++mt) {
            const int c0 = 16 * mt + 4 * q;
            float4 hn;
            hn.x = fmaf((h[mt][0] - mu) * rstd, ln2_w[c0 + 0], ln2_b[c0 + 0]);
            hn.y = fmaf((h[mt][1] - mu) * rstd, ln2_w[c0 + 1], ln2_b[c0 + 1]);
            hn.z = fmaf((h[mt][2] - mu) * rstd, ln2_w[c0 + 2], ln2_b[c0 + 2]);
            hn.w = fmaf((h[mt][3] - mu) * rstd, ln2_w[c0 + 3], ln2_b[c0 + 3]);
            *(float4*)&hnbuf[r][c0] = hn;
        }
    }
    __syncthreads();

    for (int o = lane; o < ROWS * 20; o += 64) {
        const int rr = o / 20, ka = o % 20;
        float p = head_b[ka];
#pragma unroll
        for (int c = 0; c < HIDDEN; ++c)
            p = fmaf(hnbuf[rr][c], head_W[ka * HIDDEN + c], p);
        const int k = ka >> 2, a = ka & 3;     // out[k][b][a], shape (5,B,4)
        out[(size_t)k * Btot * 4 + (size_t)(g * ROWS + rr) * 4 + a] = p;
    }
}

extern "C" void kernel_launch(void* const* d_in, const int* in_sizes, int n_in,
                              void* d_out, int out_size, void* d_ws, size_t ws_size,
                              hipStream_t stream) {
    const float* x         = (const float*)d_in[0];
    const float* W_in      = (const float*)d_in[1];
    const float* b_in      = (const float*)d_in[2];
    const float* tau_param = (const float*)d_in[3];
    const float* W_rec     = (const float*)d_in[4];
    const float* ln1_w     = (const float*)d_in[5];
    const float* ln1_b     = (const float*)d_in[6];
    const float* ln2_w     = (const float*)d_in[7];
    const float* ln2_b     = (const float*)d_in[8];
    const float* head_W    = (const float*)d_in[9];
    const float* head_b    = (const float*)d_in[10];

    const int B = in_sizes[0] / (T_STEPS * N_INPUT);   // 4096
    dim3 grid(B / ROWS), block(64);                    // 256 blocks x 1 wave
    hipLaunchKernelGGL(hlnn_wave, grid, block, 0, stream,
                       x, W_in, b_in, tau_param, W_rec, ln1_w, ln1_b,
                       ln2_w, ln2_b, head_W, head_b, (float*)d_out, B);
}

// Round 2
// 1340.185 us; speedup vs baseline: 1.9988x; 1.9988x over previous
//
#include <hip/hip_runtime.h>

#define HIDDEN  64
#define T_STEPS 2048
#define N_INPUT 5
#define DT      0.1f
#define LN_EPS  1e-5f
#define ROWS    16                     // batch rows per block (MFMA N)
#define TANH_K  2.885390081777927f     // 2*log2(e)

typedef short bf16x8 __attribute__((ext_vector_type(8)));
typedef float f32x4  __attribute__((ext_vector_type(4)));

union FragU { uint4 u4; unsigned int u[4]; unsigned short us[8]; bf16x8 v; };

__device__ __forceinline__ unsigned short bf16_trunc(float f) {
    return (unsigned short)(__float_as_uint(f) >> 16);
}
__device__ __forceinline__ float bf16_hi_f32(float f) {
    return __uint_as_float(__float_as_uint(f) & 0xFFFF0000u);
}
// [lo16 = f0.hi16 | hi16 = f1.hi16] in ONE v_perm_b32
__device__ __forceinline__ unsigned int pack_hi2(float f0, float f1) {
    return __builtin_amdgcn_perm(__float_as_uint(f1), __float_as_uint(f0), 0x07060302u);
}

#define MFMA(A, B, C) __builtin_amdgcn_mfma_f32_16x16x32_bf16((A), (B), (C), 0, 0, 0)

// 4 waves per 16-row group. Wave w owns hidden cols [16w,16w+16): 9 MFMAs
// per step (3 x-side MFMAs hoisted off the critical path into the previous
// step's tanh shadow; 6 h-side MFMAs as two 3-deep chains merged by one add).
// Stats exchange: raw per-lane partials -> LDS -> barrier -> 8xb128 broadcast
// reads (no serial in-wave pre-reduce before the barrier).
__global__ __launch_bounds__(256, 1) void hlnn_mfma4(
    const float* __restrict__ x, const float* __restrict__ W_in,
    const float* __restrict__ b_in, const float* __restrict__ tau_param,
    const float* __restrict__ W_rec, const float* __restrict__ ln1_w,
    const float* __restrict__ ln1_b, const float* __restrict__ ln2_w,
    const float* __restrict__ ln2_b, const float* __restrict__ head_W,
    const float* __restrict__ head_b, float* __restrict__ out, int Btot)
{
    const int tid  = threadIdx.x;
    const int lane = tid & 63;
    const int w    = tid >> 6;        // wave id = hidden 16-col tile
    const int r    = lane & 15;       // batch row within group
    const int q    = lane >> 4;       // quad
    const int g    = blockIdx.x;      // 16-row group

    // h transposed transport: [row][hidden] bf16, 72-ushort (144B) row stride
    __shared__ unsigned short hHi[ROWS][72];
    __shared__ unsigned short hLo[ROWS][72];
    __shared__ float2 stats2[ROWS][18];        // [row][4w+q] raw partials (+2 pad)
    __shared__ float  hnbuf[ROWS][68];         // epilogue LN2 output

    // ---- static A fragments: A[m=r][k=q*8+j] = W_rec[k][16w+m], split hi/lo
    FragU A_hi[2], A_lo[2];
    const int cfrag = 16 * w + r;              // global hidden col of this lane's A
#pragma unroll
    for (int kk = 0; kk < 2; ++kk)
#pragma unroll
        for (int j = 0; j < 8; ++j) {
            const float wv = W_rec[(kk * 32 + q * 8 + j) * HIDDEN + cfrag];
            A_hi[kk].us[j] = bf16_trunc(wv);
            A_lo[kk].us[j] = bf16_trunc(wv - bf16_hi_f32(wv));
        }
    FragU Ax_hi, Ax_lo;                        // W_in^T, K=32 (rows >=5 zero)
#pragma unroll
    for (int j = 0; j < 8; ++j) {
        const int kg = q * 8 + j;
        const float wv = (kg < N_INPUT) ? W_in[kg * HIDDEN + cfrag] : 0.0f;
        Ax_hi.us[j] = bf16_trunc(wv);
        Ax_lo.us[j] = bf16_trunc(wv - bf16_hi_f32(wv));
    }

    // ---- per-lane elementwise constants: lane owns (c = 16w+4q+e, row r)
    float w1K[4], b1K[4], dec4[4], ln2w4[4], ln2b4[4];
    f32x4 cinit;
#pragma unroll
    for (int e = 0; e < 4; ++e) {
        const int c = 16 * w + 4 * q + e;
        w1K[e]  = ln1_w[c] * TANH_K;           // fold 2*log2(e) into LN1 affine
        b1K[e]  = ln1_b[c] * TANH_K;
        const float tp  = tau_param[c];
        const float tau = (tp > 20.0f) ? tp : log1pf(expf(tp));   // softplus
        dec4[e]  = 1.0f - DT / tau;
        ln2w4[e] = ln2_w[c];  ln2b4[e] = ln2_b[c];
        cinit[e] = b_in[c];                    // bias folded into x-side C-init
    }

    const float* xrow = x + (size_t)(g * ROWS + r) * T_STEPS * N_INPUT;

    // ---- preheader: Bx(t=0) -> accx(t=0); Bh = 0 (h0 = 0)
    f32x4 accx;
    {
        const float x0 = xrow[0], x1 = xrow[1], x2 = xrow[2], x3 = xrow[3], x4 = xrow[4];
        FragU BxH, BxL;
        BxH.u[0] = pack_hi2(x0, x1); BxH.u[1] = pack_hi2(x2, x3);
        BxH.u[2] = pack_hi2(x4, 0.f); BxH.u[3] = 0u;
        BxL.u[0] = pack_hi2(x0 - bf16_hi_f32(x0), x1 - bf16_hi_f32(x1));
        BxL.u[1] = pack_hi2(x2 - bf16_hi_f32(x2), x3 - bf16_hi_f32(x3));
        BxL.u[2] = pack_hi2(x4 - bf16_hi_f32(x4), 0.f); BxL.u[3] = 0u;
        accx = MFMA(Ax_hi.v, BxH.v, cinit);
        accx = MFMA(Ax_hi.v, BxL.v, accx);
        accx = MFMA(Ax_lo.v, BxH.v, accx);
    }

    FragU Bh[2], Bl[2];
    Bh[0].u4 = make_uint4(0,0,0,0); Bh[1].u4 = make_uint4(0,0,0,0);
    Bl[0].u4 = make_uint4(0,0,0,0); Bl[1].u4 = make_uint4(0,0,0,0);
    const f32x4 zero4 = {0.f, 0.f, 0.f, 0.f};
    float h[4] = {0.f, 0.f, 0.f, 0.f};

    for (int t = 0; t < T_STEPS; ++t) {
        // prefetch next step's x (5 scalars; hidden under MFMA+stats phases)
        const size_t toff = (size_t)((t + 1 < T_STEPS) ? (t + 1) : t) * N_INPUT;
        const float xf0 = xrow[toff + 0], xf1 = xrow[toff + 1], xf2 = xrow[toff + 2],
                    xf3 = xrow[toff + 3], xf4 = xrow[toff + 4];

        // h-side MFMAs: two independent 3-deep chains; chain0 seeded with the
        // prehoisted x-side result (accx), chain1 with zero. 6x16 = 96 busy.
        f32x4 a0 = MFMA(A_hi[0].v, Bh[0].v, accx);
        f32x4 a1 = MFMA(A_hi[1].v, Bh[1].v, zero4);
        a0 = MFMA(A_hi[0].v, Bl[0].v, a0);
        a1 = MFMA(A_hi[1].v, Bl[1].v, a1);
        a0 = MFMA(A_lo[0].v, Bh[0].v, a0);
        a1 = MFMA(A_lo[1].v, Bh[1].v, a1);
        const f32x4 acc = a0 + a1;

        // raw per-lane stats partial -> LDS (no pre-reduce before barrier)
        const float p1 = (acc[0] + acc[1]) + (acc[2] + acc[3]);
        const float p2 = fmaf(acc[0], acc[0], fmaf(acc[1], acc[1],
                         fmaf(acc[2], acc[2], acc[3] * acc[3])));
        stats2[r][4 * w + q] = make_float2(p1, p2);
        __syncthreads();                                   // barrier 1

        // row reduce: 16 partials, 8x b128 (4 q-lanes share addr -> broadcast)
        const float4* sp = (const float4*)&stats2[r][0];
        const float4 v0 = sp[0], v1 = sp[1], v2 = sp[2], v3 = sp[3];
        const float4 v4 = sp[4], v5 = sp[5], v6 = sp[6], v7 = sp[7];
        const float sum = (((v0.x + v0.z) + (v1.x + v1.z)) + ((v2.x + v2.z) + (v3.x + v3.z)))
                        + (((v4.x + v4.z) + (v5.x + v5.z)) + ((v6.x + v6.z) + (v7.x + v7.z)));
        const float ssq = (((v0.y + v0.w) + (v1.y + v1.w)) + ((v2.y + v2.w) + (v3.y + v3.w)))
                        + (((v4.y + v4.w) + (v5.y + v5.w)) + ((v6.y + v6.w) + (v7.y + v7.w)));

        // x-side MFMAs for t+1: pack Bx and issue now -> runs under tanh phase
        {
            FragU nBxH, nBxL;
            nBxH.u[0] = pack_hi2(xf0, xf1); nBxH.u[1] = pack_hi2(xf2, xf3);
            nBxH.u[2] = pack_hi2(xf4, 0.f); nBxH.u[3] = 0u;
            nBxL.u[0] = pack_hi2(xf0 - bf16_hi_f32(xf0), xf1 - bf16_hi_f32(xf1));
            nBxL.u[1] = pack_hi2(xf2 - bf16_hi_f32(xf2), xf3 - bf16_hi_f32(xf3));
            nBxL.u[2] = pack_hi2(xf4 - bf16_hi_f32(xf4), 0.f); nBxL.u[3] = 0u;
            accx = MFMA(Ax_hi.v, nBxH.v, cinit);
            accx = MFMA(Ax_hi.v, nBxL.v, accx);
            accx = MFMA(Ax_lo.v, nBxH.v, accx);
        }

        const float mu   = sum * (1.0f / 64.0f);
        float var        = fmaf(mu, -mu, ssq * (1.0f / 64.0f));
        var              = fmaxf(var, 0.0f);
        const float rstd = __builtin_amdgcn_rsqf(var + LN_EPS);

        // f = tanh(LN(pre)); h = clip(decay*h + dt*f)
#pragma unroll
        for (int e = 0; e < 4; ++e) {
            const float a1c = rstd * w1K[e];
            const float tt  = fmaf(acc[e], a1c, fmaf(-mu, a1c, b1K[e]));
            const float ex  = __builtin_amdgcn_exp2f(tt);
            const float rc  = __builtin_amdgcn_rcpf(ex + 1.0f);
            const float dtf = fmaf(DT, ex, -DT) * rc;      // DT * tanh
            const float hv  = fmaf(dec4[e], h[e], dtf);
            h[e] = fminf(fmaxf(hv, -10.0f), 10.0f);
        }

        // split h -> bf16 hi/lo, write transposed to LDS
        const int c0 = 16 * w + 4 * q;
        {
            const float l0 = h[0] - bf16_hi_f32(h[0]), l1v = h[1] - bf16_hi_f32(h[1]);
            const float l2 = h[2] - bf16_hi_f32(h[2]), l3v = h[3] - bf16_hi_f32(h[3]);
            *(uint2*)&hHi[r][c0] = make_uint2(pack_hi2(h[0], h[1]), pack_hi2(h[2], h[3]));
            *(uint2*)&hLo[r][c0] = make_uint2(pack_hi2(l0, l1v),   pack_hi2(l2, l3v));
        }
        __syncthreads();                                   // barrier 2

        // B-frags for next step: lane reads row r, k = kk*32 + q*8 .. +7
        Bh[0].u4 = *(const uint4*)&hHi[r][0 * 32 + q * 8];
        Bl[0].u4 = *(const uint4*)&hLo[r][0 * 32 + q * 8];
        Bh[1].u4 = *(const uint4*)&hHi[r][1 * 32 + q * 8];
        Bl[1].u4 = *(const uint4*)&hLo[r][1 * 32 + q * 8];
    }

    // ---- epilogue: LN2 on final h (same stats pattern), then 5x4 heads ----
    {
        const float p1 = (h[0] + h[1]) + (h[2] + h[3]);
        const float p2 = fmaf(h[0], h[0], fmaf(h[1], h[1], fmaf(h[2], h[2], h[3] * h[3])));
        __syncthreads();                                   // protect stats2 reuse
        stats2[r][4 * w + q] = make_float2(p1, p2);
        __syncthreads();
        const float4* sp = (const float4*)&stats2[r][0];
        const float4 v0 = sp[0], v1 = sp[1], v2 = sp[2], v3 = sp[3];
        const float4 v4 = sp[4], v5 = sp[5], v6 = sp[6], v7 = sp[7];
        const float sum = (((v0.x + v0.z) + (v1.x + v1.z)) + ((v2.x + v2.z) + (v3.x + v3.z)))
                        + (((v4.x + v4.z) + (v5.x + v5.z)) + ((v6.x + v6.z) + (v7.x + v7.z)));
        const float ssq = (((v0.y + v0.w) + (v1.y + v1.w)) + ((v2.y + v2.w) + (v3.y + v3.w)))
                        + (((v4.y + v4.w) + (v5.y + v5.w)) + ((v6.y + v6.w) + (v7.y + v7.w)));
        const float mu   = sum * (1.0f / 64.0f);
        float var        = fmaf(mu, -mu, ssq * (1.0f / 64.0f));
        var              = fmaxf(var, 0.0f);
        const float rstd = __builtin_amdgcn_rsqf(var + LN_EPS);
        const int c0 = 16 * w + 4 * q;
        float4 hn;
        hn.x = fmaf((h[0] - mu) * rstd, ln2w4[0], ln2b4[0]);
        hn.y = fmaf((h[1] - mu) * rstd, ln2w4[1], ln2b4[1]);
        hn.z = fmaf((h[2] - mu) * rstd, ln2w4[2], ln2b4[2]);
        hn.w = fmaf((h[3] - mu) * rstd, ln2w4[3], ln2b4[3]);
        *(float4*)&hnbuf[r][c0] = hn;
    }
    __syncthreads();

    for (int o = tid; o < ROWS * 20; o += 256) {
        const int rr = o / 20, ka = o % 20;
        float p = head_b[ka];
#pragma unroll
        for (int c = 0; c < HIDDEN; ++c)
            p = fmaf(hnbuf[rr][c], head_W[ka * HIDDEN + c], p);
        const int k = ka >> 2, a = ka & 3;     // out[k][b][a], shape (5,B,4)
        out[(size_t)k * Btot * 4 + (size_t)(g * ROWS + rr) * 4 + a] = p;
    }
}

extern "C" void kernel_launch(void* const* d_in, const int* in_sizes, int n_in,
                              void* d_out, int out_size, void* d_ws, size_t ws_size,
                              hipStream_t stream) {
    const float* x         = (const float*)d_in[0];
    const float* W_in      = (const float*)d_in[1];
    const float* b_in      = (const float*)d_in[2];
    const float* tau_param = (const float*)d_in[3];
    const float* W_rec     = (const float*)d_in[4];
    const float* ln1_w     = (const float*)d_in[5];
    const float* ln1_b     = (const float*)d_in[6];
    const float* ln2_w     = (const float*)d_in[7];
    const float* ln2_b     = (const float*)d_in[8];
    const float* head_W    = (const float*)d_in[9];
    const float* head_b    = (const float*)d_in[10];

    const int B = in_sizes[0] / (T_STEPS * N_INPUT);   // 4096
    dim3 grid(B / ROWS), block(256);                   // 256 blocks x 4 waves
    hipLaunchKernelGGL(hlnn_mfma4, grid, block, 0, stream,
                       x, W_in, b_in, tau_param, W_rec, ln1_w, ln1_b,
                       ln2_w, ln2_b, head_W, head_b, (float*)d_out, B);
}